// Round 11
// baseline (133.332 us; speedup 1.0000x reference)
//
#include <hip/hip_runtime.h>

// Chamfer distance — single fused kernel + 8B counter memset.
// pts = img_render_points[0]      : 4096 x 2 f32 (slice 0)
// refs = ref_catheter_skeleton[1] : 32768 x 2 f32 (last slice; flip is neutral)
//
// ||p-r||^2 = ||p||^2 + (||r||^2 - 2 p.r)
// Phase 1: pairwise partial mins (packed v_pk_fma_f32 path, 16 own pts/thread,
//          broadcast LDS reads). Phase 2 (after grid barrier): 96 blocks fold
//          slices -> sqrt -> 96 partial sums. Phase 3: block 0 final sum.
// Grid barrier: 512 blocks all co-resident (launch_bounds(256,2) -> >=2
// blocks/CU capacity, 512 = 2*256 exactly); release fence + atomicAdd +
// spin + acquire fence. One atomic per block per barrier. Deterministic.

typedef float v2f __attribute__((ext_vector_type(2)));

constexpr int N_PTS = 4096;
constexpr int M_REF = 32768;
constexpr int P_OWN = 16;    // own points per thread (phase 1)
constexpr int S_STG = 128;   // staged points per block = 64 packed pairs
constexpr int R_SLC = 256;   // row slices = M_REF / S_STG
constexpr int C_SLC = 32;    // col slices = N_PTS / S_STG
constexpr unsigned int NBLK = 512;

__device__ __forceinline__ void grid_barrier(unsigned int* counter)
{
    __syncthreads();
    if (threadIdx.x == 0) {
        __threadfence();                       // release: flush this XCD's L2
        atomicAdd(counter, 1u);                // device-scope
        while (__hip_atomic_load(counter, __ATOMIC_RELAXED,
                                 __HIP_MEMORY_SCOPE_AGENT) < NBLK) {
            __builtin_amdgcn_s_sleep(2);
        }
        __threadfence();                       // acquire: invalidate stale lines
    }
    __syncthreads();
}

__global__ __launch_bounds__(256, 2) void chamfer_fused_kernel(
    const float2* __restrict__ pts, const float2* __restrict__ refs,
    float* __restrict__ rowpart,   // [R_SLC][N_PTS]
    float* __restrict__ colpart,   // [C_SLC][M_REF]
    float* __restrict__ partial,   // [96]
    unsigned int* __restrict__ counters,  // [2], zeroed by memset each call
    float* __restrict__ out)
{
    __shared__ float4 sxy[S_STG / 2];  // (-2x0, -2x1, -2y0, -2y1) per pair
    __shared__ float2 sz [S_STG / 2];  // (||r0||^2, ||r1||^2)     per pair
    __shared__ float4 red[256];
    __shared__ float  ssum[4];
    const int tid = threadIdx.x, b = blockIdx.x;

    // ---------------- Phase 1: pairwise partial mins -----------------------
    {
        const float2* own; const float2* oth; float* part;
        int ownBase, sbase;
        if (b < 256) {                        // rows: own = pts, staged = refs
            own = pts;  oth = refs;
            ownBase = tid * P_OWN;
            sbase   = b * S_STG;
            part    = rowpart + b * N_PTS + ownBase;
        } else {                              // cols: own = refs, staged = pts
            const int bb = b - 256;
            own = refs; oth = pts;
            ownBase = (bb & 7) * 4096 + tid * P_OWN;
            sbase   = (bb >> 3) * S_STG;
            part    = colpart + (bb >> 3) * M_REF + ownBase;
        }

        if (tid < S_STG / 2) {
            const float4 rr = ((const float4*)(oth + sbase))[tid];  // (x0,y0,x1,y1)
            sxy[tid] = make_float4(-2.f * rr.x, -2.f * rr.z, -2.f * rr.y, -2.f * rr.w);
            sz [tid] = make_float2(fmaf(rr.x, rr.x, rr.y * rr.y),
                                   fmaf(rr.z, rr.z, rr.w * rr.w));
        }

        v2f px2[P_OWN], py2[P_OWN];
        float mn[P_OWN];
        {
            const float4* o4 = (const float4*)(own + ownBase);
            #pragma unroll
            for (int q = 0; q < P_OWN / 2; ++q) {
                const float4 o = o4[q];
                px2[2 * q]     = (v2f){o.x, o.x}; py2[2 * q]     = (v2f){o.y, o.y};
                px2[2 * q + 1] = (v2f){o.z, o.z}; py2[2 * q + 1] = (v2f){o.w, o.w};
            }
            #pragma unroll
            for (int k = 0; k < P_OWN; ++k) mn[k] = 3.0e38f;
        }
        __syncthreads();

        #pragma unroll 2
        for (int j = 0; j < S_STG / 2; ++j) {   // 64 packed pairs, broadcast reads
            const float4 xy = sxy[j];
            const float2 zz = sz[j];
            const v2f rx2 = (v2f){xy.x, xy.y};
            const v2f ry2 = (v2f){xy.z, xy.w};
            const v2f rz2 = (v2f){zz.x, zz.y};
            #pragma unroll
            for (int k = 0; k < P_OWN; ++k) {
                const v2f d2 = px2[k] * rx2 + (py2[k] * ry2 + rz2);  // 2x pk_fma
                mn[k] = fminf(fminf(mn[k], d2.x), d2.y);             // v_min3
            }
        }

        float4* w = (float4*)part;
        #pragma unroll
        for (int q = 0; q < P_OWN / 4; ++q)
            w[q] = make_float4(mn[4 * q], mn[4 * q + 1], mn[4 * q + 2], mn[4 * q + 3]);
    }

    grid_barrier(&counters[0]);

    // ---------------- Phase 2: fold (blocks 0..95) -------------------------
    if (b < 96) {
        const float4* rowpart4 = (const float4*)rowpart;
        const float4* colpart4 = (const float4*)colpart;
        float dsum = 0.f;

        if (b < 32) {                                    // rows
            const int lane = tid & 31, sc = tid >> 5;    // 8 chunks x 32 slices
            const int f4 = b * 32 + lane;
            float4 m = rowpart4[(sc * 32) * (N_PTS / 4) + f4];
            for (int s = 1; s < 32; ++s) {
                const float4 v = rowpart4[(sc * 32 + s) * (N_PTS / 4) + f4];
                m.x = fminf(m.x, v.x); m.y = fminf(m.y, v.y);
                m.z = fminf(m.z, v.z); m.w = fminf(m.w, v.w);
            }
            red[sc * 32 + lane] = m;
            __syncthreads();
            if (tid < 32) {
                float4 mm = red[tid];
                #pragma unroll
                for (int c = 1; c < 8; ++c) {
                    const float4 v = red[c * 32 + tid];
                    mm.x = fminf(mm.x, v.x); mm.y = fminf(mm.y, v.y);
                    mm.z = fminf(mm.z, v.z); mm.w = fminf(mm.w, v.w);
                }
                const int f4g = b * 32 + tid;
                const float4 pa = ((const float4*)pts)[2 * f4g];
                const float4 pb = ((const float4*)pts)[2 * f4g + 1];
                dsum = sqrtf(fmaxf(mm.x + fmaf(pa.x, pa.x, pa.y * pa.y), 1e-12f))
                     + sqrtf(fmaxf(mm.y + fmaf(pa.z, pa.z, pa.w * pa.w), 1e-12f))
                     + sqrtf(fmaxf(mm.z + fmaf(pb.x, pb.x, pb.y * pb.y), 1e-12f))
                     + sqrtf(fmaxf(mm.w + fmaf(pb.z, pb.z, pb.w * pb.w), 1e-12f));
            }
        } else {                                         // cols
            const int cb = b - 32;
            const int lane = tid & 127, sc = tid >> 7;   // 2 chunks x 16 slices
            const int f4 = cb * 128 + lane;
            float4 m = colpart4[(sc * 16) * (M_REF / 4) + f4];
            for (int s = 1; s < 16; ++s) {
                const float4 v = colpart4[(sc * 16 + s) * (M_REF / 4) + f4];
                m.x = fminf(m.x, v.x); m.y = fminf(m.y, v.y);
                m.z = fminf(m.z, v.z); m.w = fminf(m.w, v.w);
            }
            red[sc * 128 + lane] = m;
            __syncthreads();
            if (tid < 128) {
                float4 mm = red[tid];
                const float4 v = red[128 + tid];
                mm.x = fminf(mm.x, v.x); mm.y = fminf(mm.y, v.y);
                mm.z = fminf(mm.z, v.z); mm.w = fminf(mm.w, v.w);
                const int f4g = cb * 128 + tid;
                const float4 ra = ((const float4*)refs)[2 * f4g];
                const float4 rb = ((const float4*)refs)[2 * f4g + 1];
                dsum = sqrtf(fmaxf(mm.x + fmaf(ra.x, ra.x, ra.y * ra.y), 1e-12f))
                     + sqrtf(fmaxf(mm.y + fmaf(ra.z, ra.z, ra.w * ra.w), 1e-12f))
                     + sqrtf(fmaxf(mm.z + fmaf(rb.x, rb.x, rb.y * rb.y), 1e-12f))
                     + sqrtf(fmaxf(mm.w + fmaf(rb.z, rb.z, rb.w * rb.w), 1e-12f));
            }
        }

        #pragma unroll
        for (int off = 32; off > 0; off >>= 1) dsum += __shfl_down(dsum, off, 64);
        const int lane = tid & 63, wave = tid >> 6;
        if (lane == 0) ssum[wave] = dsum;
        __syncthreads();
        if (tid == 0) partial[b] = ssum[0] + ssum[1] + ssum[2] + ssum[3];
    }

    grid_barrier(&counters[1]);

    // ---------------- Phase 3: final sum (block 0, plain store) ------------
    if (b == 0) {
        float d = (tid < 96) ? partial[tid] : 0.f;
        #pragma unroll
        for (int off = 32; off > 0; off >>= 1) d += __shfl_down(d, off, 64);
        const int lane = tid & 63, wave = tid >> 6;
        if (lane == 0) ssum[wave] = d;
        __syncthreads();
        if (tid == 0) out[0] = ssum[0] + ssum[1] + ssum[2] + ssum[3];
    }
}

extern "C" void kernel_launch(void* const* d_in, const int* in_sizes, int n_in,
                              void* d_out, int out_size, void* d_ws, size_t ws_size,
                              hipStream_t stream) {
    const float2* pts  = (const float2*)d_in[0];            // circle 0 (offset 0)
    const float2* refs = ((const float2*)d_in[1]) + M_REF;  // last (=2nd) skeleton slice

    float* rowpart = (float*)d_ws;                          // 256*4096  = 4 MB
    float* colpart = rowpart + R_SLC * N_PTS;               //  32*32768 = 4 MB
    float* partial = colpart + C_SLC * M_REF;               // 96 f32
    unsigned int* counters = (unsigned int*)(partial + 96); // [2]
    float* out = (float*)d_out;

    hipMemsetAsync(counters, 0, 2 * sizeof(unsigned int), stream);
    chamfer_fused_kernel<<<NBLK, 256, 0, stream>>>(pts, refs, rowpart, colpart,
                                                   partial, counters, out);
}

// Round 12
// 33.064 us; speedup vs baseline: 4.0325x; 4.0325x over previous
//
#include <hip/hip_runtime.h>

// Chamfer distance — 2 dispatches, no memsets, no barriers.
// pts = img_render_points[0]      : 4096 x 2 f32 (slice 0)
// refs = ref_catheter_skeleton[1] : 32768 x 2 f32 (last slice; flip is neutral)
//
// ||p-r||^2 = ||p||^2 + (||r||^2 - 2 p.r)
// D1: packed pairwise partial mins (proven round-10 main); block 0 also zeroes
//     out[0] (safe: dispatch boundary orders it before D2's atomics).
// D2: proven round-10 fold (96 blocks); each block atomicAdd's its partial sum
//     into out[0] (96 float atomics total — round 1 proved this passes).

typedef float v2f __attribute__((ext_vector_type(2)));

constexpr int N_PTS = 4096;
constexpr int M_REF = 32768;
constexpr int P_OWN = 16;    // own points per thread (main)
constexpr int S_STG = 128;   // staged points per block = 64 packed pairs
constexpr int R_SLC = 256;   // row slices = M_REF / S_STG
constexpr int C_SLC = 32;    // col slices = N_PTS / S_STG

// ---------------- Kernel 1: pairwise partial mins (packed math) ------------
__global__ __launch_bounds__(256) void chamfer_main_kernel(
    const float2* __restrict__ pts, const float2* __restrict__ refs,
    float* __restrict__ rowpart,   // [R_SLC][N_PTS]
    float* __restrict__ colpart,   // [C_SLC][M_REF]
    float* __restrict__ out)
{
    __shared__ float4 sxy[S_STG / 2];  // (-2x0, -2x1, -2y0, -2y1) per pair
    __shared__ float2 sz [S_STG / 2];  // (||r0||^2, ||r1||^2)     per pair
    const int tid = threadIdx.x, b = blockIdx.x;

    if (b == 0 && tid == 0) out[0] = 0.f;   // zero accumulator for dispatch 2

    const float2* own; const float2* oth; float* part;
    int ownBase, sbase;
    if (b < 256) {                        // rows: own = pts, staged = refs
        own = pts;  oth = refs;
        ownBase = tid * P_OWN;
        sbase   = b * S_STG;
        part    = rowpart + b * N_PTS + ownBase;
    } else {                              // cols: own = refs, staged = pts
        const int bb = b - 256;
        own = refs; oth = pts;
        ownBase = (bb & 7) * 4096 + tid * P_OWN;
        sbase   = (bb >> 3) * S_STG;
        part    = colpart + (bb >> 3) * M_REF + ownBase;
    }

    // Stage 64 packed pairs (threads 0..63), one float4 = two points each.
    if (tid < S_STG / 2) {
        const float4 rr = ((const float4*)(oth + sbase))[tid];  // (x0,y0,x1,y1)
        sxy[tid] = make_float4(-2.f * rr.x, -2.f * rr.z, -2.f * rr.y, -2.f * rr.w);
        sz [tid] = make_float2(fmaf(rr.x, rr.x, rr.y * rr.y),
                               fmaf(rr.z, rr.z, rr.w * rr.w));
    }

    // 16 own points/thread, splatted for packed math.
    v2f px2[P_OWN], py2[P_OWN];
    float mn[P_OWN];
    {
        const float4* o4 = (const float4*)(own + ownBase);
        #pragma unroll
        for (int q = 0; q < P_OWN / 2; ++q) {
            const float4 o = o4[q];
            px2[2 * q]     = (v2f){o.x, o.x}; py2[2 * q]     = (v2f){o.y, o.y};
            px2[2 * q + 1] = (v2f){o.z, o.z}; py2[2 * q + 1] = (v2f){o.w, o.w};
        }
        #pragma unroll
        for (int k = 0; k < P_OWN; ++k) mn[k] = 3.0e38f;
    }
    __syncthreads();

    for (int j = 0; j < S_STG / 2; ++j) {     // 64 packed pairs, broadcast reads
        const float4 xy = sxy[j];
        const float2 zz = sz[j];
        const v2f rx2 = (v2f){xy.x, xy.y};
        const v2f ry2 = (v2f){xy.z, xy.w};
        const v2f rz2 = (v2f){zz.x, zz.y};
        #pragma unroll
        for (int k = 0; k < P_OWN; ++k) {
            const v2f d2 = px2[k] * rx2 + (py2[k] * ry2 + rz2);  // 2x v_pk_fma_f32
            mn[k] = fminf(fminf(mn[k], d2.x), d2.y);             // v_min3_f32
        }
    }

    // 64 B contiguous per thread, written exactly once.
    float4* w = (float4*)part;
    #pragma unroll
    for (int q = 0; q < P_OWN / 4; ++q)
        w[q] = make_float4(mn[4 * q], mn[4 * q + 1], mn[4 * q + 2], mn[4 * q + 3]);
}

// ---------------- Kernel 2: fold + final accumulate ------------------------
// 96 blocks x 256: b<32 rows (128 pts each, 8 chunks x 32 slices),
//                  b>=32 cols (512 refs each, 2 chunks x 16 slices).
// Ends with ONE atomicAdd per block into out[0].
__global__ __launch_bounds__(256) void chamfer_fold_kernel(
    const float2* __restrict__ pts, const float2* __restrict__ refs,
    const float4* __restrict__ rowpart4,   // [R_SLC][N_PTS/4]
    const float4* __restrict__ colpart4,   // [C_SLC][M_REF/4]
    float* __restrict__ out)
{
    __shared__ float4 red[256];
    __shared__ float ssum[4];
    const int tid = threadIdx.x, b = blockIdx.x;
    float dsum = 0.f;

    if (b < 32) {                                    // rows
        const int lane = tid & 31, sc = tid >> 5;    // 8 chunks x 32 slices
        const int f4 = b * 32 + lane;
        float4 m = rowpart4[(sc * 32) * (N_PTS / 4) + f4];
        for (int s = 1; s < 32; ++s) {
            const float4 v = rowpart4[(sc * 32 + s) * (N_PTS / 4) + f4];
            m.x = fminf(m.x, v.x); m.y = fminf(m.y, v.y);
            m.z = fminf(m.z, v.z); m.w = fminf(m.w, v.w);
        }
        red[sc * 32 + lane] = m;
        __syncthreads();
        if (tid < 32) {
            float4 mm = red[tid];
            #pragma unroll
            for (int c = 1; c < 8; ++c) {
                const float4 v = red[c * 32 + tid];
                mm.x = fminf(mm.x, v.x); mm.y = fminf(mm.y, v.y);
                mm.z = fminf(mm.z, v.z); mm.w = fminf(mm.w, v.w);
            }
            const int f4g = b * 32 + tid;
            const float4 pa = ((const float4*)pts)[2 * f4g];
            const float4 pb = ((const float4*)pts)[2 * f4g + 1];
            dsum = sqrtf(fmaxf(mm.x + fmaf(pa.x, pa.x, pa.y * pa.y), 1e-12f))
                 + sqrtf(fmaxf(mm.y + fmaf(pa.z, pa.z, pa.w * pa.w), 1e-12f))
                 + sqrtf(fmaxf(mm.z + fmaf(pb.x, pb.x, pb.y * pb.y), 1e-12f))
                 + sqrtf(fmaxf(mm.w + fmaf(pb.z, pb.z, pb.w * pb.w), 1e-12f));
        }
    } else {                                         // cols
        const int cb = b - 32;
        const int lane = tid & 127, sc = tid >> 7;   // 2 chunks x 16 slices
        const int f4 = cb * 128 + lane;
        float4 m = colpart4[(sc * 16) * (M_REF / 4) + f4];
        for (int s = 1; s < 16; ++s) {
            const float4 v = colpart4[(sc * 16 + s) * (M_REF / 4) + f4];
            m.x = fminf(m.x, v.x); m.y = fminf(m.y, v.y);
            m.z = fminf(m.z, v.z); m.w = fminf(m.w, v.w);
        }
        red[sc * 128 + lane] = m;
        __syncthreads();
        if (tid < 128) {
            float4 mm = red[tid];
            const float4 v = red[128 + tid];
            mm.x = fminf(mm.x, v.x); mm.y = fminf(mm.y, v.y);
            mm.z = fminf(mm.z, v.z); mm.w = fminf(mm.w, v.w);
            const int f4g = cb * 128 + tid;
            const float4 ra = ((const float4*)refs)[2 * f4g];
            const float4 rb = ((const float4*)refs)[2 * f4g + 1];
            dsum = sqrtf(fmaxf(mm.x + fmaf(ra.x, ra.x, ra.y * ra.y), 1e-12f))
                 + sqrtf(fmaxf(mm.y + fmaf(ra.z, ra.z, ra.w * ra.w), 1e-12f))
                 + sqrtf(fmaxf(mm.z + fmaf(rb.x, rb.x, rb.y * rb.y), 1e-12f))
                 + sqrtf(fmaxf(mm.w + fmaf(rb.z, rb.z, rb.w * rb.w), 1e-12f));
        }
    }

    // Deterministic block reduce, then one device atomic per block (96 total).
    #pragma unroll
    for (int off = 32; off > 0; off >>= 1) dsum += __shfl_down(dsum, off, 64);
    const int lane = tid & 63, wave = tid >> 6;
    if (lane == 0) ssum[wave] = dsum;
    __syncthreads();
    if (tid == 0) atomicAdd(out, ssum[0] + ssum[1] + ssum[2] + ssum[3]);
}

extern "C" void kernel_launch(void* const* d_in, const int* in_sizes, int n_in,
                              void* d_out, int out_size, void* d_ws, size_t ws_size,
                              hipStream_t stream) {
    const float2* pts  = (const float2*)d_in[0];            // circle 0 (offset 0)
    const float2* refs = ((const float2*)d_in[1]) + M_REF;  // last (=2nd) skeleton slice

    float* rowpart = (float*)d_ws;                          // 256*4096  = 4 MB
    float* colpart = rowpart + R_SLC * N_PTS;               //  32*32768 = 4 MB
    float* out = (float*)d_out;

    chamfer_main_kernel<<<512, 256, 0, stream>>>(pts, refs, rowpart, colpart, out);
    chamfer_fold_kernel<<<96, 256, 0, stream>>>(pts, refs,
                                                (const float4*)rowpart,
                                                (const float4*)colpart, out);
}

// Round 14
// 31.831 us; speedup vs baseline: 4.1888x; 1.0388x over previous
//
#include <hip/hip_runtime.h>

// Chamfer distance — 2 dispatches, no memsets, no barriers.
// pts = img_render_points[0]      : 4096 x 2 f32 (slice 0)
// refs = ref_catheter_skeleton[1] : 32768 x 2 f32 (last slice; flip is neutral)
//
// ||p-r||^2 = ||p||^2 + (||r||^2 - 2 p.r)
// D1: pairwise partial mins with FORCED v_pk_fma_f32 (inline asm — the v2f
//     ext-vector path scalarized: round 9/10 was neutral, round-6 counters
//     show ~2x the packed instr count). 1.5 instr/pair.
// D2: fold (96 blocks) + one atomicAdd per block into out[0].

typedef float v2f __attribute__((ext_vector_type(2)));

constexpr int N_PTS = 4096;
constexpr int M_REF = 32768;
constexpr int P_OWN = 16;    // own points per thread (main)
constexpr int S_STG = 128;   // staged points per block = 64 packed pairs
constexpr int R_SLC = 256;   // row slices = M_REF / S_STG
constexpr int C_SLC = 32;    // col slices = N_PTS / S_STG

__device__ __forceinline__ v2f pk_fma(v2f a, v2f b, v2f c) {
    v2f d;
    asm("v_pk_fma_f32 %0, %1, %2, %3" : "=v"(d) : "v"(a), "v"(b), "v"(c));
    return d;
}

// ---------------- Kernel 1: pairwise partial mins (packed math) ------------
// Grid: 512 blocks x 256 threads.
//  rows (b < 256):  own = all 4096 pts (256 thr x 16), staged = refs slice b
//  cols (b >= 256): own = refs chunk (bb&7)*4096+..., staged = pts slice (bb>>3)
__global__ __launch_bounds__(256) void chamfer_main_kernel(
    const float2* __restrict__ pts, const float2* __restrict__ refs,
    float* __restrict__ rowpart,   // [R_SLC][N_PTS]
    float* __restrict__ colpart,   // [C_SLC][M_REF]
    float* __restrict__ out)
{
    __shared__ float4 sxy[S_STG / 2];  // (-2x0, -2x1, -2y0, -2y1) per pair
    __shared__ float2 sz [S_STG / 2];  // (||r0||^2, ||r1||^2)     per pair
    const int tid = threadIdx.x, b = blockIdx.x;

    if (b == 0 && tid == 0) out[0] = 0.f;   // zero accumulator for dispatch 2

    const float2* own; const float2* oth; float* part;
    int ownBase, sbase;
    if (b < 256) {                        // rows: own = pts, staged = refs
        own = pts;  oth = refs;
        ownBase = tid * P_OWN;
        sbase   = b * S_STG;
        part    = rowpart + b * N_PTS + ownBase;
    } else {                              // cols: own = refs, staged = pts
        const int bb = b - 256;
        own = refs; oth = pts;
        ownBase = (bb & 7) * 4096 + tid * P_OWN;
        sbase   = (bb >> 3) * S_STG;
        part    = colpart + (bb >> 3) * M_REF + ownBase;
    }

    // Stage 64 packed pairs (threads 0..63), one float4 = two points each.
    if (tid < S_STG / 2) {
        const float4 rr = ((const float4*)(oth + sbase))[tid];  // (x0,y0,x1,y1)
        sxy[tid] = make_float4(-2.f * rr.x, -2.f * rr.z, -2.f * rr.y, -2.f * rr.w);
        sz [tid] = make_float2(fmaf(rr.x, rr.x, rr.y * rr.y),
                               fmaf(rr.z, rr.z, rr.w * rr.w));
    }

    // 16 own points/thread, splatted into true packed registers.
    v2f px2[P_OWN], py2[P_OWN];
    float mn[P_OWN];
    {
        const float4* o4 = (const float4*)(own + ownBase);
        #pragma unroll
        for (int q = 0; q < P_OWN / 2; ++q) {
            const float4 o = o4[q];
            px2[2 * q]     = (v2f){o.x, o.x}; py2[2 * q]     = (v2f){o.y, o.y};
            px2[2 * q + 1] = (v2f){o.z, o.z}; py2[2 * q + 1] = (v2f){o.w, o.w};
        }
        #pragma unroll
        for (int k = 0; k < P_OWN; ++k) mn[k] = 3.0e38f;
    }
    __syncthreads();

    #pragma unroll 4
    for (int j = 0; j < S_STG / 2; ++j) {     // 64 packed pairs, broadcast reads
        const float4 xy = sxy[j];
        const float2 zz = sz[j];
        const v2f rx2 = (v2f){xy.x, xy.y};
        const v2f ry2 = (v2f){xy.z, xy.w};
        const v2f rz2 = (v2f){zz.x, zz.y};
        #pragma unroll
        for (int k = 0; k < P_OWN; ++k) {
            const v2f t  = pk_fma(py2[k], ry2, rz2);   // v_pk_fma_f32 (forced)
            const v2f d2 = pk_fma(px2[k], rx2, t);     // v_pk_fma_f32 (forced)
            mn[k] = fminf(fminf(mn[k], d2.x), d2.y);   // v_min3_f32
        }
    }

    // 64 B contiguous per thread, written exactly once.
    float4* w = (float4*)part;
    #pragma unroll
    for (int q = 0; q < P_OWN / 4; ++q)
        w[q] = make_float4(mn[4 * q], mn[4 * q + 1], mn[4 * q + 2], mn[4 * q + 3]);
}

// ---------------- Kernel 2: fold + final accumulate ------------------------
// 96 blocks x 256: b<32 rows (128 pts each, 8 chunks x 32 slices),
//                  b>=32 cols (512 refs each, 2 chunks x 16 slices).
__global__ __launch_bounds__(256) void chamfer_fold_kernel(
    const float2* __restrict__ pts, const float2* __restrict__ refs,
    const float4* __restrict__ rowpart4,   // [R_SLC][N_PTS/4]
    const float4* __restrict__ colpart4,   // [C_SLC][M_REF/4]
    float* __restrict__ out)
{
    __shared__ float4 red[256];
    __shared__ float ssum[4];
    const int tid = threadIdx.x, b = blockIdx.x;
    float dsum = 0.f;

    if (b < 32) {                                    // rows
        const int lane = tid & 31, sc = tid >> 5;    // 8 chunks x 32 slices
        const int f4 = b * 32 + lane;
        float4 m = rowpart4[(sc * 32) * (N_PTS / 4) + f4];
        for (int s = 1; s < 32; ++s) {
            const float4 v = rowpart4[(sc * 32 + s) * (N_PTS / 4) + f4];
            m.x = fminf(m.x, v.x); m.y = fminf(m.y, v.y);
            m.z = fminf(m.z, v.z); m.w = fminf(m.w, v.w);
        }
        red[sc * 32 + lane] = m;
        __syncthreads();
        if (tid < 32) {
            float4 mm = red[tid];
            #pragma unroll
            for (int c = 1; c < 8; ++c) {
                const float4 v = red[c * 32 + tid];
                mm.x = fminf(mm.x, v.x); mm.y = fminf(mm.y, v.y);
                mm.z = fminf(mm.z, v.z); mm.w = fminf(mm.w, v.w);
            }
            const int f4g = b * 32 + tid;
            const float4 pa = ((const float4*)pts)[2 * f4g];
            const float4 pb = ((const float4*)pts)[2 * f4g + 1];
            dsum = sqrtf(fmaxf(mm.x + fmaf(pa.x, pa.x, pa.y * pa.y), 1e-12f))
                 + sqrtf(fmaxf(mm.y + fmaf(pa.z, pa.z, pa.w * pa.w), 1e-12f))
                 + sqrtf(fmaxf(mm.z + fmaf(pb.x, pb.x, pb.y * pb.y), 1e-12f))
                 + sqrtf(fmaxf(mm.w + fmaf(pb.z, pb.z, pb.w * pb.w), 1e-12f));
        }
    } else {                                         // cols
        const int cb = b - 32;
        const int lane = tid & 127, sc = tid >> 7;   // 2 chunks x 16 slices
        const int f4 = cb * 128 + lane;
        float4 m = colpart4[(sc * 16) * (M_REF / 4) + f4];
        for (int s = 1; s < 16; ++s) {
            const float4 v = colpart4[(sc * 16 + s) * (M_REF / 4) + f4];
            m.x = fminf(m.x, v.x); m.y = fminf(m.y, v.y);
            m.z = fminf(m.z, v.z); m.w = fminf(m.w, v.w);
        }
        red[sc * 128 + lane] = m;
        __syncthreads();
        if (tid < 128) {
            float4 mm = red[tid];
            const float4 v = red[128 + tid];
            mm.x = fminf(mm.x, v.x); mm.y = fminf(mm.y, v.y);
            mm.z = fminf(mm.z, v.z); mm.w = fminf(mm.w, v.w);
            const int f4g = cb * 128 + tid;
            const float4 ra = ((const float4*)refs)[2 * f4g];
            const float4 rb = ((const float4*)refs)[2 * f4g + 1];
            dsum = sqrtf(fmaxf(mm.x + fmaf(ra.x, ra.x, ra.y * ra.y), 1e-12f))
                 + sqrtf(fmaxf(mm.y + fmaf(ra.z, ra.z, ra.w * ra.w), 1e-12f))
                 + sqrtf(fmaxf(mm.z + fmaf(rb.x, rb.x, rb.y * rb.y), 1e-12f))
                 + sqrtf(fmaxf(mm.w + fmaf(rb.z, rb.z, rb.w * rb.w), 1e-12f));
        }
    }

    // Deterministic block reduce, then one device atomic per block (96 total).
    #pragma unroll
    for (int off = 32; off > 0; off >>= 1) dsum += __shfl_down(dsum, off, 64);
    const int lane = tid & 63, wave = tid >> 6;
    if (lane == 0) ssum[wave] = dsum;
    __syncthreads();
    if (tid == 0) atomicAdd(out, ssum[0] + ssum[1] + ssum[2] + ssum[3]);
}

extern "C" void kernel_launch(void* const* d_in, const int* in_sizes, int n_in,
                              void* d_out, int out_size, void* d_ws, size_t ws_size,
                              hipStream_t stream) {
    const float2* pts  = (const float2*)d_in[0];            // circle 0 (offset 0)
    const float2* refs = ((const float2*)d_in[1]) + M_REF;  // last (=2nd) skeleton slice

    float* rowpart = (float*)d_ws;                          // 256*4096  = 4 MB
    float* colpart = rowpart + R_SLC * N_PTS;               //  32*32768 = 4 MB
    float* out = (float*)d_out;

    chamfer_main_kernel<<<512, 256, 0, stream>>>(pts, refs, rowpart, colpart, out);
    chamfer_fold_kernel<<<96, 256, 0, stream>>>(pts, refs,
                                                (const float4*)rowpart,
                                                (const float4*)colpart, out);
}

// Round 15
// 31.322 us; speedup vs baseline: 4.2568x; 1.0162x over previous
//
#include <hip/hip_runtime.h>

// Chamfer distance — 2 dispatches, no memsets, no barriers.
// pts = img_render_points[0]      : 4096 x 2 f32 (slice 0)
// refs = ref_catheter_skeleton[1] : 32768 x 2 f32 (last slice; flip is neutral)
//
// ||p-r||^2 = ||p||^2 + (||r||^2 - 2 p.r)
// D1 (1024 blocks, 4 waves/SIMD): pairwise partial mins. One ds_read_b128 per
//     staged PAIR (raw coords); -2 folded into splatted own registers; ||r||^2
//     rebuilt with 2 packed ops/pair (amortized over 8 own pts). Forced
//     v_pk_fma_f32 inline asm (v2f C-arithmetic scalarizes).
// D2: fold (96 blocks, proven) + one atomicAdd per block into out[0].

typedef float v2f __attribute__((ext_vector_type(2)));

constexpr int N_PTS = 4096;
constexpr int M_REF = 32768;
constexpr int P_OWN = 8;     // own points per thread (main)
constexpr int S_STG = 128;   // staged points per block = 64 packed pairs
constexpr int R_SLC = 256;   // row slices = M_REF / S_STG
constexpr int C_SLC = 32;    // col slices = N_PTS / S_STG

__device__ __forceinline__ v2f pk_fma(v2f a, v2f b, v2f c) {
    v2f d;
    asm("v_pk_fma_f32 %0, %1, %2, %3" : "=v"(d) : "v"(a), "v"(b), "v"(c));
    return d;
}
__device__ __forceinline__ v2f pk_mul(v2f a, v2f b) {
    v2f d;
    asm("v_pk_mul_f32 %0, %1, %2" : "=v"(d) : "v"(a), "v"(b));
    return d;
}

// ---------------- Kernel 1: pairwise partial mins --------------------------
// Grid: 1024 blocks x 256 threads (4 blocks/CU -> 4 waves/SIMD).
//  rows (b < 512):  chunk = b&1 (2 x 2048 pts), slice = b>>1 (256 ref slices)
//  cols (b >= 512): chunk = bb&15 (16 x 2048 refs), slice = bb>>4 (32 pt slices)
__global__ __launch_bounds__(256) void chamfer_main_kernel(
    const float2* __restrict__ pts, const float2* __restrict__ refs,
    float* __restrict__ rowpart,   // [R_SLC][N_PTS]
    float* __restrict__ colpart,   // [C_SLC][M_REF]
    float* __restrict__ out)
{
    __shared__ float4 sxy[S_STG / 2];  // (x0, x1, y0, y1) per staged pair, 1 KB
    const int tid = threadIdx.x, b = blockIdx.x;

    if (b == 0 && tid == 0) out[0] = 0.f;   // zero accumulator for dispatch 2

    const float2* own; const float2* oth; float* part;
    int ownBase, sbase;
    if (b < 512) {                        // rows: own = pts, staged = refs
        own = pts;  oth = refs;
        ownBase = (b & 1) * 2048 + tid * P_OWN;
        sbase   = (b >> 1) * S_STG;
        part    = rowpart + (b >> 1) * N_PTS + ownBase;
    } else {                              // cols: own = refs, staged = pts
        const int bb = b - 512;
        own = refs; oth = pts;
        ownBase = (bb & 15) * 2048 + tid * P_OWN;
        sbase   = (bb >> 4) * S_STG;
        part    = colpart + (bb >> 4) * M_REF + ownBase;
    }

    // Stage 64 pairs (threads 0..63): one float4 = two raw points, shuffled.
    if (tid < S_STG / 2) {
        const float4 rr = ((const float4*)(oth + sbase))[tid];  // (x0,y0,x1,y1)
        sxy[tid] = make_float4(rr.x, rr.z, rr.y, rr.w);         // (x0,x1,y0,y1)
    }

    // 8 own points/thread, splatted with the -2 factor folded in.
    v2f px2[P_OWN], py2[P_OWN];
    float mn[P_OWN];
    {
        const float4* o4 = (const float4*)(own + ownBase);
        #pragma unroll
        for (int q = 0; q < P_OWN / 2; ++q) {
            const float4 o = o4[q];
            px2[2 * q]     = (v2f){-2.f * o.x, -2.f * o.x};
            py2[2 * q]     = (v2f){-2.f * o.y, -2.f * o.y};
            px2[2 * q + 1] = (v2f){-2.f * o.z, -2.f * o.z};
            py2[2 * q + 1] = (v2f){-2.f * o.w, -2.f * o.w};
        }
        #pragma unroll
        for (int k = 0; k < P_OWN; ++k) mn[k] = 3.0e38f;
    }
    __syncthreads();

    #pragma unroll 4
    for (int j = 0; j < S_STG / 2; ++j) {   // 64 pairs: ONE ds_read_b128 each
        const float4 xy = sxy[j];
        const v2f rx2 = (v2f){xy.x, xy.y};
        const v2f ry2 = (v2f){xy.z, xy.w};
        const v2f rz2 = pk_fma(rx2, rx2, pk_mul(ry2, ry2));  // (||r0||^2,||r1||^2)
        #pragma unroll
        for (int k = 0; k < P_OWN; ++k) {
            const v2f t  = pk_fma(py2[k], ry2, rz2);   // v_pk_fma_f32
            const v2f d2 = pk_fma(px2[k], rx2, t);     // v_pk_fma_f32
            mn[k] = fminf(fminf(mn[k], d2.x), d2.y);   // v_min3_f32
        }
    }

    // 32 B contiguous per thread, written exactly once.
    float4* w = (float4*)part;
    #pragma unroll
    for (int q = 0; q < P_OWN / 4; ++q)
        w[q] = make_float4(mn[4 * q], mn[4 * q + 1], mn[4 * q + 2], mn[4 * q + 3]);
}

// ---------------- Kernel 2: fold + final accumulate (proven) ---------------
// 96 blocks x 256: b<32 rows (128 pts each, 8 chunks x 32 slices),
//                  b>=32 cols (512 refs each, 2 chunks x 16 slices).
__global__ __launch_bounds__(256) void chamfer_fold_kernel(
    const float2* __restrict__ pts, const float2* __restrict__ refs,
    const float4* __restrict__ rowpart4,   // [R_SLC][N_PTS/4]
    const float4* __restrict__ colpart4,   // [C_SLC][M_REF/4]
    float* __restrict__ out)
{
    __shared__ float4 red[256];
    __shared__ float ssum[4];
    const int tid = threadIdx.x, b = blockIdx.x;
    float dsum = 0.f;

    if (b < 32) {                                    // rows
        const int lane = tid & 31, sc = tid >> 5;    // 8 chunks x 32 slices
        const int f4 = b * 32 + lane;
        float4 m = rowpart4[(sc * 32) * (N_PTS / 4) + f4];
        for (int s = 1; s < 32; ++s) {
            const float4 v = rowpart4[(sc * 32 + s) * (N_PTS / 4) + f4];
            m.x = fminf(m.x, v.x); m.y = fminf(m.y, v.y);
            m.z = fminf(m.z, v.z); m.w = fminf(m.w, v.w);
        }
        red[sc * 32 + lane] = m;
        __syncthreads();
        if (tid < 32) {
            float4 mm = red[tid];
            #pragma unroll
            for (int c = 1; c < 8; ++c) {
                const float4 v = red[c * 32 + tid];
                mm.x = fminf(mm.x, v.x); mm.y = fminf(mm.y, v.y);
                mm.z = fminf(mm.z, v.z); mm.w = fminf(mm.w, v.w);
            }
            const int f4g = b * 32 + tid;
            const float4 pa = ((const float4*)pts)[2 * f4g];
            const float4 pb = ((const float4*)pts)[2 * f4g + 1];
            dsum = sqrtf(fmaxf(mm.x + fmaf(pa.x, pa.x, pa.y * pa.y), 1e-12f))
                 + sqrtf(fmaxf(mm.y + fmaf(pa.z, pa.z, pa.w * pa.w), 1e-12f))
                 + sqrtf(fmaxf(mm.z + fmaf(pb.x, pb.x, pb.y * pb.y), 1e-12f))
                 + sqrtf(fmaxf(mm.w + fmaf(pb.z, pb.z, pb.w * pb.w), 1e-12f));
        }
    } else {                                         // cols
        const int cb = b - 32;
        const int lane = tid & 127, sc = tid >> 7;   // 2 chunks x 16 slices
        const int f4 = cb * 128 + lane;
        float4 m = colpart4[(sc * 16) * (M_REF / 4) + f4];
        for (int s = 1; s < 16; ++s) {
            const float4 v = colpart4[(sc * 16 + s) * (M_REF / 4) + f4];
            m.x = fminf(m.x, v.x); m.y = fminf(m.y, v.y);
            m.z = fminf(m.z, v.z); m.w = fminf(m.w, v.w);
        }
        red[sc * 128 + lane] = m;
        __syncthreads();
        if (tid < 128) {
            float4 mm = red[tid];
            const float4 v = red[128 + tid];
            mm.x = fminf(mm.x, v.x); mm.y = fminf(mm.y, v.y);
            mm.z = fminf(mm.z, v.z); mm.w = fminf(mm.w, v.w);
            const int f4g = cb * 128 + tid;
            const float4 ra = ((const float4*)refs)[2 * f4g];
            const float4 rb = ((const float4*)refs)[2 * f4g + 1];
            dsum = sqrtf(fmaxf(mm.x + fmaf(ra.x, ra.x, ra.y * ra.y), 1e-12f))
                 + sqrtf(fmaxf(mm.y + fmaf(ra.z, ra.z, ra.w * ra.w), 1e-12f))
                 + sqrtf(fmaxf(mm.z + fmaf(rb.x, rb.x, rb.y * rb.y), 1e-12f))
                 + sqrtf(fmaxf(mm.w + fmaf(rb.z, rb.z, rb.w * rb.w), 1e-12f));
        }
    }

    // Deterministic block reduce, then one device atomic per block (96 total).
    #pragma unroll
    for (int off = 32; off > 0; off >>= 1) dsum += __shfl_down(dsum, off, 64);
    const int lane = tid & 63, wave = tid >> 6;
    if (lane == 0) ssum[wave] = dsum;
    __syncthreads();
    if (tid == 0) atomicAdd(out, ssum[0] + ssum[1] + ssum[2] + ssum[3]);
}

extern "C" void kernel_launch(void* const* d_in, const int* in_sizes, int n_in,
                              void* d_out, int out_size, void* d_ws, size_t ws_size,
                              hipStream_t stream) {
    const float2* pts  = (const float2*)d_in[0];            // circle 0 (offset 0)
    const float2* refs = ((const float2*)d_in[1]) + M_REF;  // last (=2nd) skeleton slice

    float* rowpart = (float*)d_ws;                          // 256*4096  = 4 MB
    float* colpart = rowpart + R_SLC * N_PTS;               //  32*32768 = 4 MB
    float* out = (float*)d_out;

    chamfer_main_kernel<<<1024, 256, 0, stream>>>(pts, refs, rowpart, colpart, out);
    chamfer_fold_kernel<<<96, 256, 0, stream>>>(pts, refs,
                                                (const float4*)rowpart,
                                                (const float4*)colpart, out);
}